// Round 3
// baseline (236.448 us; speedup 1.0000x reference)
//
#include <hip/hip_runtime.h>
#include <hip/hip_bf16.h>
#include <stdint.h>

#define NH 8
#define D 8
#define HH 48
#define WW 48
#define NQ (HH*WW)          // 2304
#define BB 2
#define PACK (BB*NH*NQ*D)   // 294912 floats per tensor

// ---------------------------------------------------------------------------
// Kernel 1: repack fp32 [B,H,W,192] -> fp32 head-major Q/K/V [b*8+h][n][8]
// Q pre-scaled by dkh^-0.5 = 1/sqrt(8).
// ---------------------------------------------------------------------------
__global__ __launch_bounds__(256) void repack_kernel(const float* __restrict__ in,
                                                     float* __restrict__ ws) {
    int tid = blockIdx.x * blockDim.x + threadIdx.x;   // [0, 3*PACK)
    int which = tid / PACK;          // 0=Q,1=K,2=V
    int r = tid - which * PACK;
    int d = r & 7;
    int n2 = r >> 3;
    int n = n2 % NQ;
    int bh = n2 / NQ;                // b*8+h
    int h = bh & 7;
    int c = which * 64 + h * 8 + d;
    float v = in[((size_t)(bh >> 3) * NQ + n) * 192 + c];
    if (which == 0) v *= 0.35355339059327373f;   // 8^-0.5
    ws[tid] = v;
}

// ---------------------------------------------------------------------------
// Kernel 2: attention. 8 lanes per query; lane s handles keys == s (mod 8).
// logit[q=(y,x), k=(y2,x2)] = q.k + q.rel_w[x2-x+47] + q.rel_h[y2-y+47]
// Fixed-shift softmax (M0 = 12), 3-step shfl_xor merge over the 8 lanes.
// ---------------------------------------------------------------------------
__global__ __launch_bounds__(256) void attn_kernel(const float* __restrict__ ws,
                                                   const float* __restrict__ relw,
                                                   const float* __restrict__ relh,
                                                   float* __restrict__ out) {
    const float* Qf = ws;
    const float* Kf = ws + PACK;
    const float* Vf = ws + 2 * PACK;

    const int bx = blockIdx.x;
    const int bh = bx / 72;                 // 0..15  (b*8+h)
    const int qbase = (bx % 72) * 32;
    const int lane = threadIdx.x & 63;
    const int wv = threadIdx.x >> 6;
    const int g = lane >> 3;                // query group within wave
    const int s = lane & 7;                 // key-residue lane
    const int n = qbase + wv * 8 + g;       // query index 0..2303
    const int y = n / WW;
    const int x = n - y * WW;

    // load query (8 fp32, pre-scaled)
    const float4* qp = (const float4*)(Qf + ((size_t)bh * NQ + n) * D);
    const float4 qa = qp[0];
    const float4 qb = qp[1];

    // per-lane qw for the 6 x2-residues this lane will see: x2 = s + 8u
    float qw[6];
#pragma unroll
    for (int u = 0; u < 6; ++u) {
        int m = s + 8 * u - x + 47;         // in [0,94]
        float4 ta = *(const float4*)(relw + m * 8);
        float4 tb = *(const float4*)(relw + m * 8 + 4);
        qw[u] = qa.x * ta.x + qa.y * ta.y + qa.z * ta.z + qa.w * ta.w
              + qb.x * tb.x + qb.y * tb.y + qb.z * tb.z + qb.w * tb.w;
    }

    float l = 0.0f;
    float a0 = 0, a1 = 0, a2 = 0, a3 = 0, a4 = 0, a5 = 0, a6 = 0, a7 = 0;

    const float* kb = Kf + ((size_t)bh * NQ + s) * D;
    const float* vb = Vf + ((size_t)bh * NQ + s) * D;

    for (int r = 0; r < HH; ++r) {
        // qh for this key row (same for all u)
        float4 ha = *(const float4*)(relh + (r - y + 47) * 8);
        float4 hb = *(const float4*)(relh + (r - y + 47) * 8 + 4);
        float qh = qa.x * ha.x + qa.y * ha.y + qa.z * ha.z + qa.w * ha.w
                 + qb.x * hb.x + qb.y * hb.y + qb.z * hb.z + qb.w * hb.w;

        const float* kr = kb + r * (WW * D);
        const float* vr = vb + r * (WW * D);
#pragma unroll
        for (int u = 0; u < 6; ++u) {
            float4 ka = *(const float4*)(kr + u * 64);
            float4 k2 = *(const float4*)(kr + u * 64 + 4);
            float dt = qa.x * ka.x + qa.y * ka.y + qa.z * ka.z + qa.w * ka.w
                     + qb.x * k2.x + qb.y * k2.y + qb.z * k2.z + qb.w * k2.w;
            float lg = dt + qw[u] + qh;
            float p = __expf(lg - 12.0f);   // fixed-shift softmax
            l += p;
            float4 va = *(const float4*)(vr + u * 64);
            float4 v2 = *(const float4*)(vr + u * 64 + 4);
            a0 = fmaf(p, va.x, a0); a1 = fmaf(p, va.y, a1);
            a2 = fmaf(p, va.z, a2); a3 = fmaf(p, va.w, a3);
            a4 = fmaf(p, v2.x, a4); a5 = fmaf(p, v2.y, a5);
            a6 = fmaf(p, v2.z, a6); a7 = fmaf(p, v2.w, a7);
        }
    }

    // merge the 8 partial softmax states (fixed shift: plain sums)
#pragma unroll
    for (int mm = 1; mm < 8; mm <<= 1) {
        l  += __shfl_xor(l, mm);
        a0 += __shfl_xor(a0, mm); a1 += __shfl_xor(a1, mm);
        a2 += __shfl_xor(a2, mm); a3 += __shfl_xor(a3, mm);
        a4 += __shfl_xor(a4, mm); a5 += __shfl_xor(a5, mm);
        a6 += __shfl_xor(a6, mm); a7 += __shfl_xor(a7, mm);
    }

    if (s == 0) {
        float inv = 1.0f / l;
        int b = bh >> 3, h = bh & 7;
        float* op = out + ((size_t)(b * NQ + n) * 64 + h * 8);
        float4 o0 = make_float4(a0 * inv, a1 * inv, a2 * inv, a3 * inv);
        float4 o1 = make_float4(a4 * inv, a5 * inv, a6 * inv, a7 * inv);
        *(float4*)(op)     = o0;
        *(float4*)(op + 4) = o1;
    }
}

extern "C" void kernel_launch(void* const* d_in, const int* in_sizes, int n_in,
                              void* d_out, int out_size, void* d_ws, size_t ws_size,
                              hipStream_t stream) {
    const float* in   = (const float*)d_in[0];
    const float* relw = (const float*)d_in[1];
    const float* relh = (const float*)d_in[2];
    float* ws = (float*)d_ws;
    float* out = (float*)d_out;

    repack_kernel<<<(3 * PACK) / 256, 256, 0, stream>>>(in, ws);
    attn_kernel<<<16 * 72, 256, 0, stream>>>(ws, relw, relh, out);
}